// Round 2
// baseline (1049.641 us; speedup 1.0000x reference)
//
#include <hip/hip_runtime.h>
#include <stdint.h>

#define T_TOK 8192
#define HD 1024
#define ED 8
#define DD 2048
#define BM 128
#define BK 32
#define TILE_SHARED 64   // T_TOK/BM shared-expert tiles
#define TILE_MAX 200     // 64 shared + max 136 routed tiles
#define CHUNK_T 100      // tiles per hbuf chunk (2 chunks)
#define ROWCAP 25600     // 8192 shared + 17408 padded routed rows

typedef short short8 __attribute__((ext_vector_type(8)));
typedef float f32x4 __attribute__((ext_vector_type(4)));

__device__ __forceinline__ unsigned short f2bf(float f) {
  union { float f; unsigned int u; } v; v.f = f;
  unsigned int r = (v.u + 0x7fffu + ((v.u >> 16) & 1u)) >> 16;
  return (unsigned short)r;
}

__device__ __forceinline__ void gll16(const void* g, void* l) {
  __builtin_amdgcn_global_load_lds(
      (const __attribute__((address_space(1))) unsigned int*)g,
      (__attribute__((address_space(3))) unsigned int*)l, 16, 0, 0);
}

// ---------------- zero d_out ----------------
__global__ __launch_bounds__(256) void k_zero(float* __restrict__ outp) {
  size_t i = (size_t)blockIdx.x * 256 + threadIdx.x;
  ((float4*)outp)[i] = make_float4(0.f, 0.f, 0.f, 0.f);
}

// ---------------- init: counts + default assignment table ----------------
__global__ __launch_bounds__(256) void k_init(int* counts, int* tok, float* wrow) {
  int i = blockIdx.x * 256 + threadIdx.x;
  if (i < 32) counts[i] = 0;
  if (i < ROWCAP) {
    tok[i] = (i < T_TOK) ? i : 0;          // shared segment = identity; pads -> token 0
    wrow[i] = (i < T_TOK) ? 1.0f : 0.0f;   // shared weight 1, pads weight 0
  }
}

// ---------------- transpose+convert: in[R][C] fp32 -> out[C][R] bf16 ----------------
__global__ __launch_bounds__(256) void k_transpose(const float* __restrict__ in,
    unsigned short* __restrict__ outp, int R, int C) {
  __shared__ float tile[32][33];
  size_t boff = (size_t)blockIdx.z * (size_t)R * (size_t)C;
  in += boff; outp += boff;
  int c0 = blockIdx.x * 32, r0 = blockIdx.y * 32;
  int tx = threadIdx.x & 31, ty = threadIdx.x >> 5;
#pragma unroll
  for (int i = 0; i < 4; ++i)
    tile[ty + i * 8][tx] = in[(size_t)(r0 + ty + i * 8) * C + c0 + tx];
  __syncthreads();
#pragma unroll
  for (int i = 0; i < 4; ++i)
    outp[(size_t)(c0 + ty + i * 8) * R + r0 + tx] = f2bf(tile[tx][ty + i * 8]);
}

// ---------------- router: x->bf16, logits, softmax, top2, histogram ----------------
__global__ __launch_bounds__(256) void k_router(const float* __restrict__ x,
    const float* __restrict__ Wr, unsigned short* __restrict__ xb,
    int* __restrict__ counts, int* __restrict__ topE, float* __restrict__ topW) {
  __shared__ float wrT[ED * HD];  // [e][h]
  int tid = threadIdx.x;
  for (int i = tid; i < ED * HD; i += 256) {
    int e = i >> 10, h = i & (HD - 1);
    wrT[i] = Wr[h * ED + e];
  }
  __syncthreads();
  int lane = tid & 63, wave = tid >> 6;
  int t = blockIdx.x * 4 + wave;
  const float* xrow = x + (size_t)t * HD;
  unsigned short* xbrow = xb + (size_t)t * HD;
  float acc[ED] = {0, 0, 0, 0, 0, 0, 0, 0};
#pragma unroll
  for (int i = 0; i < HD / 64; ++i) {
    int h = i * 64 + lane;
    float v = xrow[h];
    xbrow[h] = f2bf(v);
#pragma unroll
    for (int e = 0; e < ED; ++e) acc[e] += v * wrT[e * HD + h];
  }
#pragma unroll
  for (int off = 32; off; off >>= 1)
#pragma unroll
    for (int e = 0; e < ED; ++e) acc[e] += __shfl_xor(acc[e], off);
  if (lane == 0) {
    float m = acc[0];
#pragma unroll
    for (int e = 1; e < ED; ++e) m = fmaxf(m, acc[e]);
    float p[ED], s = 0.f;
#pragma unroll
    for (int e = 0; e < ED; ++e) { p[e] = __expf(acc[e] - m); s += p[e]; }
    int i0 = 0;
#pragma unroll
    for (int e = 1; e < ED; ++e) if (acc[e] > acc[i0]) i0 = e;
    int i1 = -1;
#pragma unroll
    for (int e = 0; e < ED; ++e) {
      if (e == i0) continue;
      if (i1 < 0 || acc[e] > acc[i1]) i1 = e;
    }
    float p0 = p[i0] / s, p1 = p[i1] / s;
    float rs = p0 + p1 + 1e-20f;
    topE[t * 2] = i0; topE[t * 2 + 1] = i1;
    topW[t * 2] = p0 / rs; topW[t * 2 + 1] = p1 / rs;
    atomicAdd(&counts[i0], 1);
    atomicAdd(&counts[i1], 1);
  }
}

// ---------------- plan: segment bases, cursors, tile table ----------------
__global__ __launch_bounds__(256) void k_plan(const int* __restrict__ counts, int* cursor,
    int* __restrict__ tileE, int* __restrict__ tileEnd) {
  __shared__ int tstart[ED + 1], segend[ED];
  if (threadIdx.x == 0) {
    int base = T_TOK, rt = TILE_SHARED;
    for (int e = 0; e < ED; ++e) {
      int c = counts[e];
      cursor[e] = base;
      tstart[e] = rt;
      segend[e] = base + c;
      int tiles = (c + BM - 1) >> 7;
      rt += tiles;
      base += tiles << 7;
    }
    tstart[ED] = rt;
  }
  __syncthreads();
  for (int rt = threadIdx.x; rt < TILE_MAX; rt += 256) {
    int e = -1, end = 0;
    if (rt < TILE_SHARED) { e = ED; end = T_TOK; }
    else {
      for (int q = 0; q < ED; ++q)
        if (rt >= tstart[q] && rt < tstart[q + 1]) { e = q; end = segend[q]; }
    }
    tileE[rt] = e; tileEnd[rt] = end;
  }
}

// ---------------- scatter assignments ----------------
__global__ __launch_bounds__(256) void k_scatter(const int* __restrict__ topE,
    const float* __restrict__ topW, int* cursor, int* tok, float* wrow) {
  int t = blockIdx.x * 256 + threadIdx.x;
  if (t >= T_TOK) return;
#pragma unroll
  for (int s = 0; s < 2; ++s) {
    int e = topE[t * 2 + s];
    int pos = atomicAdd(&cursor[e], 1);
    tok[pos] = t;
    wrow[pos] = topW[t * 2 + s];
  }
}

// ---------------- GEMM1: hidden = silu(Xg)*(Xu), gathered rows ----------------
__global__ __launch_bounds__(256, 2) void k_gemm1(
    const unsigned short* __restrict__ xb,
    const unsigned short* __restrict__ wgt, const unsigned short* __restrict__ wut,
    const unsigned short* __restrict__ sgt, const unsigned short* __restrict__ sut,
    const int* __restrict__ tok, const int* __restrict__ tileE,
    const int* __restrict__ tileEnd, unsigned short* __restrict__ hbuf, int tileBase) {
  int lt = blockIdx.y;
  int rt = tileBase + lt;
  int e = tileE[rt];
  if (e < 0) return;
  int n0 = blockIdx.x * BM;
  int grow0 = rt * BM;   // global assignment-row base
  int hrow0 = lt * BM;   // chunk-local hbuf row base
  int segEnd = tileEnd[rt];
  const unsigned short* bg = (e == ED) ? sgt : wgt + (size_t)e * DD * HD;
  const unsigned short* bu = (e == ED) ? sut : wut + (size_t)e * DD * HD;

  __shared__ __align__(16) unsigned short As[BM * BK];
  __shared__ __align__(16) unsigned short Bg[BM * BK];
  __shared__ __align__(16) unsigned short Bu[BM * BK];

  int tid = threadIdx.x, lane = tid & 63, wave = tid >> 6;
  int wm = (wave & 1) * 64, wn = (wave >> 1) * 64;
  int kc = lane & 3;

  int ldsU[2];
  const unsigned short *pA[2], *pBg[2], *pBu[2];
#pragma unroll
  for (int r = 0; r < 2; ++r) {
    int chunk = r * 4 + wave;
    int idx = chunk * 64 + lane;
    int row = idx >> 2;
    ldsU[r] = chunk * 512;
    pA[r]  = xb + (size_t)tok[grow0 + row] * HD + kc * 8;
    pBg[r] = bg + (size_t)(n0 + row) * HD + kc * 8;
    pBu[r] = bu + (size_t)(n0 + row) * HD + kc * 8;
  }

  f32x4 zero = {0.f, 0.f, 0.f, 0.f};
  f32x4 accg[4][4], accu[4][4];
#pragma unroll
  for (int i = 0; i < 4; ++i)
#pragma unroll
    for (int j = 0; j < 4; ++j) { accg[i][j] = zero; accu[i][j] = zero; }

  for (int k0 = 0; k0 < HD; k0 += BK) {
#pragma unroll
    for (int r = 0; r < 2; ++r) {
      gll16(pA[r] + k0,  As + ldsU[r]);
      gll16(pBg[r] + k0, Bg + ldsU[r]);
      gll16(pBu[r] + k0, Bu + ldsU[r]);
    }
    __syncthreads();
    short8 af[4], bgf[4], buf_[4];
    int qk = (lane >> 4) * 8;
#pragma unroll
    for (int i = 0; i < 4; ++i) {
      af[i]   = *(const short8*)(As + (wm + i * 16 + (lane & 15)) * BK + qk);
      bgf[i]  = *(const short8*)(Bg + (wn + i * 16 + (lane & 15)) * BK + qk);
      buf_[i] = *(const short8*)(Bu + (wn + i * 16 + (lane & 15)) * BK + qk);
    }
#pragma unroll
    for (int i = 0; i < 4; ++i)
#pragma unroll
      for (int j = 0; j < 4; ++j) {
        accg[i][j] = __builtin_amdgcn_mfma_f32_16x16x32_bf16(af[i], bgf[j],  accg[i][j], 0, 0, 0);
        accu[i][j] = __builtin_amdgcn_mfma_f32_16x16x32_bf16(af[i], buf_[j], accu[i][j], 0, 0, 0);
      }
    __syncthreads();
  }

  int colB = n0 + wn + (lane & 15);
  int rowB = wm + ((lane >> 4) << 2);
#pragma unroll
  for (int i = 0; i < 4; ++i)
#pragma unroll
    for (int j = 0; j < 4; ++j)
#pragma unroll
      for (int r = 0; r < 4; ++r) {
        int lr = rowB + i * 16 + r;
        float g = accg[i][j][r], u = accu[i][j][r];
        float h = (grow0 + lr < segEnd) ? (g / (1.0f + __expf(-g))) * u : 0.0f;
        hbuf[(size_t)(hrow0 + lr) * DD + colB + j * 16] = f2bf(h);
      }
}

// ---------------- GEMM2: out[tok] += (hidden @ Wd^T) * wrow (atomic) ----------------
__global__ __launch_bounds__(256, 2) void k_gemm2(
    const unsigned short* __restrict__ hbuf,
    const unsigned short* __restrict__ wdt, const unsigned short* __restrict__ sdt,
    const int* __restrict__ tok, const int* __restrict__ tileE,
    const int* __restrict__ tileEnd, const float* __restrict__ wrow,
    float* __restrict__ outp, int tileBase) {
  int lt = blockIdx.y;
  int rt = tileBase + lt;
  int e = tileE[rt];
  if (e < 0) return;
  int n0 = blockIdx.x * BM;
  int grow0 = rt * BM;
  int hrow0 = lt * BM;
  int segEnd = tileEnd[rt];
  const unsigned short* bd = (e == ED) ? sdt : wdt + (size_t)e * HD * DD;

  __shared__ __align__(16) unsigned short As[BM * BK];
  __shared__ __align__(16) unsigned short Bs[BM * BK];

  int tid = threadIdx.x, lane = tid & 63, wave = tid >> 6;
  int wm = (wave & 1) * 64, wn = (wave >> 1) * 64;
  int kc = lane & 3;

  int ldsU[2];
  const unsigned short *pA[2], *pB[2];
#pragma unroll
  for (int r = 0; r < 2; ++r) {
    int chunk = r * 4 + wave;
    int idx = chunk * 64 + lane;
    int row = idx >> 2;
    ldsU[r] = chunk * 512;
    pA[r] = hbuf + (size_t)(hrow0 + row) * DD + kc * 8;
    pB[r] = bd + (size_t)(n0 + row) * DD + kc * 8;
  }

  f32x4 zero = {0.f, 0.f, 0.f, 0.f};
  f32x4 acc[4][4];
#pragma unroll
  for (int i = 0; i < 4; ++i)
#pragma unroll
    for (int j = 0; j < 4; ++j) acc[i][j] = zero;

  for (int k0 = 0; k0 < DD; k0 += BK) {
#pragma unroll
    for (int r = 0; r < 2; ++r) {
      gll16(pA[r] + k0, As + ldsU[r]);
      gll16(pB[r] + k0, Bs + ldsU[r]);
    }
    __syncthreads();
    short8 af[4], bf[4];
    int qk = (lane >> 4) * 8;
#pragma unroll
    for (int i = 0; i < 4; ++i) {
      af[i] = *(const short8*)(As + (wm + i * 16 + (lane & 15)) * BK + qk);
      bf[i] = *(const short8*)(Bs + (wn + i * 16 + (lane & 15)) * BK + qk);
    }
#pragma unroll
    for (int i = 0; i < 4; ++i)
#pragma unroll
      for (int j = 0; j < 4; ++j)
        acc[i][j] = __builtin_amdgcn_mfma_f32_16x16x32_bf16(af[i], bf[j], acc[i][j], 0, 0, 0);
    __syncthreads();
  }

  int colB = n0 + wn + (lane & 15);
  int rowB = wm + ((lane >> 4) << 2);
#pragma unroll
  for (int i = 0; i < 4; ++i)
#pragma unroll
    for (int r = 0; r < 4; ++r) {
      int grr = grow0 + rowB + i * 16 + r;
      if (grr < segEnd) {
        float w = wrow[grr];
        size_t ob = (size_t)tok[grr] * HD;
#pragma unroll
        for (int j = 0; j < 4; ++j)
          atomicAdd(&outp[ob + colB + j * 16], acc[i][j][r] * w);
      }
    }
}

extern "C" void kernel_launch(void* const* d_in, const int* in_sizes, int n_in,
                              void* d_out, int out_size, void* d_ws, size_t ws_size,
                              hipStream_t stream) {
  const float* x  = (const float*)d_in[0];
  const float* Wr = (const float*)d_in[1];
  const float* Wg = (const float*)d_in[2];
  const float* Wu = (const float*)d_in[3];
  const float* Wd = (const float*)d_in[4];
  const float* Sg = (const float*)d_in[5];
  const float* Su = (const float*)d_in[6];
  const float* Sd = (const float*)d_in[7];
  float* outp = (float*)d_out;

  char* ws = (char*)d_ws;
  size_t off = 0;
  auto alloc = [&](size_t bytes) -> char* {
    char* p = ws + off;
    off += (bytes + 255) & ~(size_t)255;
    return p;
  };
  unsigned short* xb  = (unsigned short*)alloc((size_t)T_TOK * HD * 2);
  unsigned short* wgt = (unsigned short*)alloc((size_t)ED * DD * HD * 2);
  unsigned short* wut = (unsigned short*)alloc((size_t)ED * DD * HD * 2);
  unsigned short* wdt = (unsigned short*)alloc((size_t)ED * HD * DD * 2);
  unsigned short* sgt = (unsigned short*)alloc((size_t)DD * HD * 2);
  unsigned short* sut = (unsigned short*)alloc((size_t)DD * HD * 2);
  unsigned short* sdt = (unsigned short*)alloc((size_t)HD * DD * 2);
  unsigned short* hbuf = (unsigned short*)alloc((size_t)CHUNK_T * BM * DD * 2);
  int* tok       = (int*)alloc((size_t)ROWCAP * 4);
  float* wrow    = (float*)alloc((size_t)ROWCAP * 4);
  int* topE      = (int*)alloc((size_t)T_TOK * 2 * 4);
  float* topW    = (float*)alloc((size_t)T_TOK * 2 * 4);
  int* counts    = (int*)alloc(128);
  int* cursor    = (int*)alloc(128);
  int* tileE     = (int*)alloc(256 * 4);
  int* tileEnd   = (int*)alloc(256 * 4);

  // Workspace guard: if d_ws is too small, launch nothing (output stays 0 ->
  // bench fails with the stub's absmax ~1.398, diagnosing ws_size as the issue).
  if (off > ws_size) return;

  k_zero<<<(out_size / 4 + 255) / 256, 256, 0, stream>>>(outp);
  k_init<<<(ROWCAP + 255) / 256, 256, 0, stream>>>(counts, tok, wrow);
  k_transpose<<<dim3(DD / 32, HD / 32, ED), 256, 0, stream>>>(Wg, wgt, HD, DD);
  k_transpose<<<dim3(DD / 32, HD / 32, ED), 256, 0, stream>>>(Wu, wut, HD, DD);
  k_transpose<<<dim3(HD / 32, DD / 32, ED), 256, 0, stream>>>(Wd, wdt, DD, HD);
  k_transpose<<<dim3(DD / 32, HD / 32, 1), 256, 0, stream>>>(Sg, sgt, HD, DD);
  k_transpose<<<dim3(DD / 32, HD / 32, 1), 256, 0, stream>>>(Su, sut, HD, DD);
  k_transpose<<<dim3(HD / 32, DD / 32, 1), 256, 0, stream>>>(Sd, sdt, DD, HD);
  k_router<<<T_TOK / 4, 256, 0, stream>>>(x, Wr, xb, counts, topE, topW);
  k_plan<<<1, 256, 0, stream>>>(counts, cursor, tileE, tileEnd);
  k_scatter<<<T_TOK / 256, 256, 0, stream>>>(topE, topW, cursor, tok, wrow);
  for (int cb = 0; cb < TILE_MAX; cb += CHUNK_T) {
    k_gemm1<<<dim3(DD / BM, CHUNK_T), 256, 0, stream>>>(xb, wgt, wut, sgt, sut, tok,
                                                        tileE, tileEnd, hbuf, cb);
    k_gemm2<<<dim3(HD / BM, CHUNK_T), 256, 0, stream>>>(hbuf, wdt, sdt, tok, tileE,
                                                        tileEnd, wrow, outp, cb);
  }
}

// Round 3
// 1042.127 us; speedup vs baseline: 1.0072x; 1.0072x over previous
//
#include <hip/hip_runtime.h>
#include <stdint.h>

#define T_TOK 8192
#define HD 1024
#define ED 8
#define DD 2048
#define BM 128
#define BK 32
#define TILE_SHARED 64   // T_TOK/BM shared-expert tiles
#define TILE_MAX 200     // 64 shared + max 136 routed tiles
#define CHUNK_T 100      // tiles per hbuf chunk (2 chunks)
#define ROWCAP 25600     // 8192 shared + 17408 padded routed rows
#define RT_TPW 16        // router: tokens per wave

typedef short short8 __attribute__((ext_vector_type(8)));
typedef float f32x4 __attribute__((ext_vector_type(4)));

__device__ __forceinline__ unsigned short f2bf(float f) {
  union { float f; unsigned int u; } v; v.f = f;
  unsigned int r = (v.u + 0x7fffu + ((v.u >> 16) & 1u)) >> 16;
  return (unsigned short)r;
}

__device__ __forceinline__ void gll16(const void* g, void* l) {
  __builtin_amdgcn_global_load_lds(
      (const __attribute__((address_space(1))) unsigned int*)g,
      (__attribute__((address_space(3))) unsigned int*)l, 16, 0, 0);
}

// ---------------- zero d_out ----------------
__global__ __launch_bounds__(256) void k_zero(float* __restrict__ outp) {
  size_t i = (size_t)blockIdx.x * 256 + threadIdx.x;
  ((float4*)outp)[i] = make_float4(0.f, 0.f, 0.f, 0.f);
}

// ---------------- init: counts + default assignment table ----------------
__global__ __launch_bounds__(256) void k_init(int* counts, int* tok, float* wrow) {
  int i = blockIdx.x * 256 + threadIdx.x;
  if (i < 32) counts[i] = 0;
  if (i < ROWCAP) {
    tok[i] = (i < T_TOK) ? i : 0;          // shared segment = identity; pads -> token 0
    wrow[i] = (i < T_TOK) ? 1.0f : 0.0f;   // shared weight 1, pads weight 0
  }
}

// ---------------- transpose+convert: in[R][C] fp32 -> out[C][R] bf16 ----------------
__global__ __launch_bounds__(256) void k_transpose(const float* __restrict__ in,
    unsigned short* __restrict__ outp, int R, int C) {
  __shared__ float tile[32][33];
  size_t boff = (size_t)blockIdx.z * (size_t)R * (size_t)C;
  in += boff; outp += boff;
  int c0 = blockIdx.x * 32, r0 = blockIdx.y * 32;
  int tx = threadIdx.x & 31, ty = threadIdx.x >> 5;
#pragma unroll
  for (int i = 0; i < 4; ++i)
    tile[ty + i * 8][tx] = in[(size_t)(r0 + ty + i * 8) * C + c0 + tx];
  __syncthreads();
#pragma unroll
  for (int i = 0; i < 4; ++i)
    outp[(size_t)(c0 + ty + i * 8) * R + r0 + tx] = f2bf(tile[tx][ty + i * 8]);
}

// ---------------- router: x->bf16, logits, softmax, top2, histogram ----------------
// 64 tokens/block (16 per wave) amortizes the 32KB Wr LDS staging that
// dominated the 4-token/block version (204us -> predicted ~25us).
__global__ __launch_bounds__(256) void k_router(const float* __restrict__ x,
    const float* __restrict__ Wr, unsigned short* __restrict__ xb,
    int* __restrict__ counts, int* __restrict__ topE, float* __restrict__ topW) {
  __shared__ float wrT[ED * HD];  // [e][h]
  int tid = threadIdx.x;
  for (int i = tid; i < ED * HD; i += 256) {
    int e = i >> 10, h = i & (HD - 1);
    wrT[i] = Wr[h * ED + e];
  }
  __syncthreads();
  int lane = tid & 63, wave = tid >> 6;
  int tbase = (blockIdx.x * 4 + wave) * RT_TPW;
  for (int tt = 0; tt < RT_TPW; ++tt) {
    int t = tbase + tt;
    const float* xrow = x + (size_t)t * HD;
    unsigned short* xbrow = xb + (size_t)t * HD;
    float acc[ED] = {0, 0, 0, 0, 0, 0, 0, 0};
#pragma unroll
    for (int i = 0; i < HD / 64; ++i) {
      int h = i * 64 + lane;
      float v = xrow[h];
      xbrow[h] = f2bf(v);
#pragma unroll
      for (int e = 0; e < ED; ++e) acc[e] += v * wrT[e * HD + h];
    }
#pragma unroll
    for (int off = 32; off; off >>= 1)
#pragma unroll
      for (int e = 0; e < ED; ++e) acc[e] += __shfl_xor(acc[e], off);
    if (lane == 0) {
      float m = acc[0];
#pragma unroll
      for (int e = 1; e < ED; ++e) m = fmaxf(m, acc[e]);
      float p[ED], s = 0.f;
#pragma unroll
      for (int e = 0; e < ED; ++e) { p[e] = __expf(acc[e] - m); s += p[e]; }
      int i0 = 0;
#pragma unroll
      for (int e = 1; e < ED; ++e) if (acc[e] > acc[i0]) i0 = e;
      int i1 = -1;
#pragma unroll
      for (int e = 0; e < ED; ++e) {
        if (e == i0) continue;
        if (i1 < 0 || acc[e] > acc[i1]) i1 = e;
      }
      float p0 = p[i0] / s, p1 = p[i1] / s;
      float rs = p0 + p1 + 1e-20f;
      topE[t * 2] = i0; topE[t * 2 + 1] = i1;
      topW[t * 2] = p0 / rs; topW[t * 2 + 1] = p1 / rs;
      atomicAdd(&counts[i0], 1);
      atomicAdd(&counts[i1], 1);
    }
  }
}

// ---------------- plan: segment bases, cursors, tile table ----------------
__global__ __launch_bounds__(256) void k_plan(const int* __restrict__ counts, int* cursor,
    int* __restrict__ tileE, int* __restrict__ tileEnd) {
  __shared__ int tstart[ED + 1], segend[ED];
  if (threadIdx.x == 0) {
    int base = T_TOK, rt = TILE_SHARED;
    for (int e = 0; e < ED; ++e) {
      int c = counts[e];
      cursor[e] = base;
      tstart[e] = rt;
      segend[e] = base + c;
      int tiles = (c + BM - 1) >> 7;
      rt += tiles;
      base += tiles << 7;
    }
    tstart[ED] = rt;
  }
  __syncthreads();
  for (int rt = threadIdx.x; rt < TILE_MAX; rt += 256) {
    int e = -1, end = 0;
    if (rt < TILE_SHARED) { e = ED; end = T_TOK; }
    else {
      for (int q = 0; q < ED; ++q)
        if (rt >= tstart[q] && rt < tstart[q + 1]) { e = q; end = segend[q]; }
    }
    tileE[rt] = e; tileEnd[rt] = end;
  }
}

// ---------------- scatter assignments ----------------
__global__ __launch_bounds__(256) void k_scatter(const int* __restrict__ topE,
    const float* __restrict__ topW, int* cursor, int* tok, float* wrow) {
  int t = blockIdx.x * 256 + threadIdx.x;
  if (t >= T_TOK) return;
#pragma unroll
  for (int s = 0; s < 2; ++s) {
    int e = topE[t * 2 + s];
    int pos = atomicAdd(&cursor[e], 1);
    tok[pos] = t;
    wrow[pos] = topW[t * 2 + s];
  }
}

// ---------------- GEMM1: hidden = silu(Xg)*(Xu), gathered rows ----------------
__global__ __launch_bounds__(256, 2) void k_gemm1(
    const unsigned short* __restrict__ xb,
    const unsigned short* __restrict__ wgt, const unsigned short* __restrict__ wut,
    const unsigned short* __restrict__ sgt, const unsigned short* __restrict__ sut,
    const int* __restrict__ tok, const int* __restrict__ tileE,
    const int* __restrict__ tileEnd, unsigned short* __restrict__ hbuf, int tileBase) {
  int lt = blockIdx.y;
  int rt = tileBase + lt;
  int e = tileE[rt];
  if (e < 0) return;
  int n0 = blockIdx.x * BM;
  int grow0 = rt * BM;   // global assignment-row base
  int hrow0 = lt * BM;   // chunk-local hbuf row base
  int segEnd = tileEnd[rt];
  const unsigned short* bg = (e == ED) ? sgt : wgt + (size_t)e * DD * HD;
  const unsigned short* bu = (e == ED) ? sut : wut + (size_t)e * DD * HD;

  __shared__ __align__(16) unsigned short As[BM * BK];
  __shared__ __align__(16) unsigned short Bg[BM * BK];
  __shared__ __align__(16) unsigned short Bu[BM * BK];

  int tid = threadIdx.x, lane = tid & 63, wave = tid >> 6;
  int wm = (wave & 1) * 64, wn = (wave >> 1) * 64;
  int kc = lane & 3;

  int ldsU[2];
  const unsigned short *pA[2], *pBg[2], *pBu[2];
#pragma unroll
  for (int r = 0; r < 2; ++r) {
    int chunk = r * 4 + wave;
    int idx = chunk * 64 + lane;
    int row = idx >> 2;
    ldsU[r] = chunk * 512;
    pA[r]  = xb + (size_t)tok[grow0 + row] * HD + kc * 8;
    pBg[r] = bg + (size_t)(n0 + row) * HD + kc * 8;
    pBu[r] = bu + (size_t)(n0 + row) * HD + kc * 8;
  }

  f32x4 zero = {0.f, 0.f, 0.f, 0.f};
  f32x4 accg[4][4], accu[4][4];
#pragma unroll
  for (int i = 0; i < 4; ++i)
#pragma unroll
    for (int j = 0; j < 4; ++j) { accg[i][j] = zero; accu[i][j] = zero; }

  for (int k0 = 0; k0 < HD; k0 += BK) {
#pragma unroll
    for (int r = 0; r < 2; ++r) {
      gll16(pA[r] + k0,  As + ldsU[r]);
      gll16(pBg[r] + k0, Bg + ldsU[r]);
      gll16(pBu[r] + k0, Bu + ldsU[r]);
    }
    __syncthreads();
    short8 af[4], bgf[4], buf_[4];
    int qk = (lane >> 4) * 8;
#pragma unroll
    for (int i = 0; i < 4; ++i) {
      af[i]   = *(const short8*)(As + (wm + i * 16 + (lane & 15)) * BK + qk);
      bgf[i]  = *(const short8*)(Bg + (wn + i * 16 + (lane & 15)) * BK + qk);
      buf_[i] = *(const short8*)(Bu + (wn + i * 16 + (lane & 15)) * BK + qk);
    }
#pragma unroll
    for (int i = 0; i < 4; ++i)
#pragma unroll
      for (int j = 0; j < 4; ++j) {
        accg[i][j] = __builtin_amdgcn_mfma_f32_16x16x32_bf16(af[i], bgf[j],  accg[i][j], 0, 0, 0);
        accu[i][j] = __builtin_amdgcn_mfma_f32_16x16x32_bf16(af[i], buf_[j], accu[i][j], 0, 0, 0);
      }
    __syncthreads();
  }

  int colB = n0 + wn + (lane & 15);
  int rowB = wm + ((lane >> 4) << 2);
#pragma unroll
  for (int i = 0; i < 4; ++i)
#pragma unroll
    for (int j = 0; j < 4; ++j)
#pragma unroll
      for (int r = 0; r < 4; ++r) {
        int lr = rowB + i * 16 + r;
        float g = accg[i][j][r], u = accu[i][j][r];
        float h = (grow0 + lr < segEnd) ? (g / (1.0f + __expf(-g))) * u : 0.0f;
        hbuf[(size_t)(hrow0 + lr) * DD + colB + j * 16] = f2bf(h);
      }
}

// ---------------- GEMM2: out[tok] += (hidden @ Wd^T) * wrow (atomic) ----------------
__global__ __launch_bounds__(256, 2) void k_gemm2(
    const unsigned short* __restrict__ hbuf,
    const unsigned short* __restrict__ wdt, const unsigned short* __restrict__ sdt,
    const int* __restrict__ tok, const int* __restrict__ tileE,
    const int* __restrict__ tileEnd, const float* __restrict__ wrow,
    float* __restrict__ outp, int tileBase) {
  int lt = blockIdx.y;
  int rt = tileBase + lt;
  int e = tileE[rt];
  if (e < 0) return;
  int n0 = blockIdx.x * BM;
  int grow0 = rt * BM;
  int hrow0 = lt * BM;
  int segEnd = tileEnd[rt];
  const unsigned short* bd = (e == ED) ? sdt : wdt + (size_t)e * HD * DD;

  __shared__ __align__(16) unsigned short As[BM * BK];
  __shared__ __align__(16) unsigned short Bs[BM * BK];

  int tid = threadIdx.x, lane = tid & 63, wave = tid >> 6;
  int wm = (wave & 1) * 64, wn = (wave >> 1) * 64;
  int kc = lane & 3;

  int ldsU[2];
  const unsigned short *pA[2], *pB[2];
#pragma unroll
  for (int r = 0; r < 2; ++r) {
    int chunk = r * 4 + wave;
    int idx = chunk * 64 + lane;
    int row = idx >> 2;
    ldsU[r] = chunk * 512;
    pA[r] = hbuf + (size_t)(hrow0 + row) * DD + kc * 8;
    pB[r] = bd + (size_t)(n0 + row) * DD + kc * 8;
  }

  f32x4 zero = {0.f, 0.f, 0.f, 0.f};
  f32x4 acc[4][4];
#pragma unroll
  for (int i = 0; i < 4; ++i)
#pragma unroll
    for (int j = 0; j < 4; ++j) acc[i][j] = zero;

  for (int k0 = 0; k0 < DD; k0 += BK) {
#pragma unroll
    for (int r = 0; r < 2; ++r) {
      gll16(pA[r] + k0, As + ldsU[r]);
      gll16(pB[r] + k0, Bs + ldsU[r]);
    }
    __syncthreads();
    short8 af[4], bf[4];
    int qk = (lane >> 4) * 8;
#pragma unroll
    for (int i = 0; i < 4; ++i) {
      af[i] = *(const short8*)(As + (wm + i * 16 + (lane & 15)) * BK + qk);
      bf[i] = *(const short8*)(Bs + (wn + i * 16 + (lane & 15)) * BK + qk);
    }
#pragma unroll
    for (int i = 0; i < 4; ++i)
#pragma unroll
      for (int j = 0; j < 4; ++j)
        acc[i][j] = __builtin_amdgcn_mfma_f32_16x16x32_bf16(af[i], bf[j], acc[i][j], 0, 0, 0);
    __syncthreads();
  }

  int colB = n0 + wn + (lane & 15);
  int rowB = wm + ((lane >> 4) << 2);
#pragma unroll
  for (int i = 0; i < 4; ++i)
#pragma unroll
    for (int r = 0; r < 4; ++r) {
      int grr = grow0 + rowB + i * 16 + r;
      if (grr < segEnd) {
        float w = wrow[grr];
        size_t ob = (size_t)tok[grr] * HD;
#pragma unroll
        for (int j = 0; j < 4; ++j)
          atomicAdd(&outp[ob + colB + j * 16], acc[i][j][r] * w);
      }
    }
}

extern "C" void kernel_launch(void* const* d_in, const int* in_sizes, int n_in,
                              void* d_out, int out_size, void* d_ws, size_t ws_size,
                              hipStream_t stream) {
  const float* x  = (const float*)d_in[0];
  const float* Wr = (const float*)d_in[1];
  const float* Wg = (const float*)d_in[2];
  const float* Wu = (const float*)d_in[3];
  const float* Wd = (const float*)d_in[4];
  const float* Sg = (const float*)d_in[5];
  const float* Su = (const float*)d_in[6];
  const float* Sd = (const float*)d_in[7];
  float* outp = (float*)d_out;

  char* ws = (char*)d_ws;
  size_t off = 0;
  auto alloc = [&](size_t bytes) -> char* {
    char* p = ws + off;
    off += (bytes + 255) & ~(size_t)255;
    return p;
  };
  unsigned short* xb  = (unsigned short*)alloc((size_t)T_TOK * HD * 2);
  unsigned short* wgt = (unsigned short*)alloc((size_t)ED * DD * HD * 2);
  unsigned short* wut = (unsigned short*)alloc((size_t)ED * DD * HD * 2);
  unsigned short* wdt = (unsigned short*)alloc((size_t)ED * HD * DD * 2);
  unsigned short* sgt = (unsigned short*)alloc((size_t)DD * HD * 2);
  unsigned short* sut = (unsigned short*)alloc((size_t)DD * HD * 2);
  unsigned short* sdt = (unsigned short*)alloc((size_t)HD * DD * 2);
  unsigned short* hbuf = (unsigned short*)alloc((size_t)CHUNK_T * BM * DD * 2);
  int* tok       = (int*)alloc((size_t)ROWCAP * 4);
  float* wrow    = (float*)alloc((size_t)ROWCAP * 4);
  int* topE      = (int*)alloc((size_t)T_TOK * 2 * 4);
  float* topW    = (float*)alloc((size_t)T_TOK * 2 * 4);
  int* counts    = (int*)alloc(128);
  int* cursor    = (int*)alloc(128);
  int* tileE     = (int*)alloc(256 * 4);
  int* tileEnd   = (int*)alloc(256 * 4);

  // Workspace guard: if d_ws is too small, launch nothing (output stays 0 ->
  // bench fails with the stub's absmax ~1.398, diagnosing ws_size as the issue).
  if (off > ws_size) return;

  k_zero<<<(out_size / 4 + 255) / 256, 256, 0, stream>>>(outp);
  k_init<<<(ROWCAP + 255) / 256, 256, 0, stream>>>(counts, tok, wrow);
  k_transpose<<<dim3(DD / 32, HD / 32, ED), 256, 0, stream>>>(Wg, wgt, HD, DD);
  k_transpose<<<dim3(DD / 32, HD / 32, ED), 256, 0, stream>>>(Wu, wut, HD, DD);
  k_transpose<<<dim3(HD / 32, DD / 32, ED), 256, 0, stream>>>(Wd, wdt, DD, HD);
  k_transpose<<<dim3(DD / 32, HD / 32, 1), 256, 0, stream>>>(Sg, sgt, HD, DD);
  k_transpose<<<dim3(DD / 32, HD / 32, 1), 256, 0, stream>>>(Su, sut, HD, DD);
  k_transpose<<<dim3(HD / 32, DD / 32, 1), 256, 0, stream>>>(Sd, sdt, DD, HD);
  k_router<<<T_TOK / (4 * RT_TPW), 256, 0, stream>>>(x, Wr, xb, counts, topE, topW);
  k_plan<<<1, 256, 0, stream>>>(counts, cursor, tileE, tileEnd);
  k_scatter<<<T_TOK / 256, 256, 0, stream>>>(topE, topW, cursor, tok, wrow);
  for (int cb = 0; cb < TILE_MAX; cb += CHUNK_T) {
    k_gemm1<<<dim3(DD / BM, CHUNK_T), 256, 0, stream>>>(xb, wgt, wut, sgt, sut, tok,
                                                        tileE, tileEnd, hbuf, cb);
    k_gemm2<<<dim3(HD / BM, CHUNK_T), 256, 0, stream>>>(hbuf, wdt, sdt, tok, tileE,
                                                        tileEnd, wrow, outp, cb);
  }
}

// Round 4
// 814.719 us; speedup vs baseline: 1.2883x; 1.2791x over previous
//
#include <hip/hip_runtime.h>
#include <stdint.h>

#define T_TOK 8192
#define HD 1024
#define ED 8
#define DD 2048
#define BM 128
#define BK 32
#define TILE_SHARED 64   // T_TOK/BM shared-expert tiles
#define TILE_MAX 200     // 64 shared + max 136 routed tiles
#define CHUNK_T 100      // tiles per hbuf chunk (2 chunks)
#define ROWCAP 25600     // 8192 shared + 17408 padded routed rows
#define RT_TPW 8         // router: tokens per wave (32/block, 256 blocks)

typedef short short8 __attribute__((ext_vector_type(8)));
typedef float f32x4 __attribute__((ext_vector_type(4)));

__device__ __forceinline__ unsigned short f2bf(float f) {
  union { float f; unsigned int u; } v; v.f = f;
  unsigned int r = (v.u + 0x7fffu + ((v.u >> 16) & 1u)) >> 16;
  return (unsigned short)r;
}

__device__ __forceinline__ void gll16(const void* g, void* l) {
  __builtin_amdgcn_global_load_lds(
      (const __attribute__((address_space(1))) unsigned int*)g,
      (__attribute__((address_space(3))) unsigned int*)l, 16, 0, 0);
}

// ---------------- zero d_out ----------------
__global__ __launch_bounds__(256) void k_zero(float* __restrict__ outp) {
  size_t i = (size_t)blockIdx.x * 256 + threadIdx.x;
  ((float4*)outp)[i] = make_float4(0.f, 0.f, 0.f, 0.f);
}

// ---------------- init: counts + default assignment table ----------------
__global__ __launch_bounds__(256) void k_init(int* counts, int* tok, float* wrow) {
  int i = blockIdx.x * 256 + threadIdx.x;
  if (i < 32) counts[i] = 0;
  if (i < ROWCAP) {
    tok[i] = (i < T_TOK) ? i : 0;          // shared segment = identity; pads -> token 0
    wrow[i] = (i < T_TOK) ? 1.0f : 0.0f;   // shared weight 1, pads weight 0
  }
}

// ---------------- transpose+convert: in[R][C] fp32 -> out[C][R] bf16 ----------------
__global__ __launch_bounds__(256) void k_transpose(const float* __restrict__ in,
    unsigned short* __restrict__ outp, int R, int C) {
  __shared__ float tile[32][33];
  size_t boff = (size_t)blockIdx.z * (size_t)R * (size_t)C;
  in += boff; outp += boff;
  int c0 = blockIdx.x * 32, r0 = blockIdx.y * 32;
  int tx = threadIdx.x & 31, ty = threadIdx.x >> 5;
#pragma unroll
  for (int i = 0; i < 4; ++i)
    tile[ty + i * 8][tx] = in[(size_t)(r0 + ty + i * 8) * C + c0 + tx];
  __syncthreads();
#pragma unroll
  for (int i = 0; i < 4; ++i)
    outp[(size_t)(c0 + ty + i * 8) * R + r0 + tx] = f2bf(tile[tx][ty + i * 8]);
}

// ---------------- router: x->bf16, logits, softmax, top2, LDS histogram ----------------
// Guideline 12: 16384 same-line global atomics serialized (~200us invariant across
// R2/R3 grid shapes). Per-block LDS histogram -> 8 global atomics per block.
__global__ __launch_bounds__(256) void k_router(const float* __restrict__ x,
    const float* __restrict__ Wr, unsigned short* __restrict__ xb,
    int* __restrict__ counts, int* __restrict__ topE, float* __restrict__ topW) {
  __shared__ float wrT[ED * HD];  // [e][h]
  __shared__ int hist[ED];
  int tid = threadIdx.x;
  if (tid < ED) hist[tid] = 0;
  for (int i = tid; i < ED * HD; i += 256) {
    int e = i >> 10, h = i & (HD - 1);
    wrT[i] = Wr[h * ED + e];
  }
  __syncthreads();
  int lane = tid & 63, wave = tid >> 6;
  int tbase = (blockIdx.x * 4 + wave) * RT_TPW;
  for (int tt = 0; tt < RT_TPW; ++tt) {
    int t = tbase + tt;
    const float* xrow = x + (size_t)t * HD;
    unsigned short* xbrow = xb + (size_t)t * HD;
    float acc[ED] = {0, 0, 0, 0, 0, 0, 0, 0};
#pragma unroll
    for (int i = 0; i < HD / 64; ++i) {
      int h = i * 64 + lane;
      float v = xrow[h];
      xbrow[h] = f2bf(v);
#pragma unroll
      for (int e = 0; e < ED; ++e) acc[e] += v * wrT[e * HD + h];
    }
#pragma unroll
    for (int off = 32; off; off >>= 1)
#pragma unroll
      for (int e = 0; e < ED; ++e) acc[e] += __shfl_xor(acc[e], off);
    if (lane == 0) {
      float m = acc[0];
#pragma unroll
      for (int e = 1; e < ED; ++e) m = fmaxf(m, acc[e]);
      float p[ED], s = 0.f;
#pragma unroll
      for (int e = 0; e < ED; ++e) { p[e] = __expf(acc[e] - m); s += p[e]; }
      int i0 = 0;
#pragma unroll
      for (int e = 1; e < ED; ++e) if (acc[e] > acc[i0]) i0 = e;
      int i1 = -1;
#pragma unroll
      for (int e = 0; e < ED; ++e) {
        if (e == i0) continue;
        if (i1 < 0 || acc[e] > acc[i1]) i1 = e;
      }
      float p0 = p[i0] / s, p1 = p[i1] / s;
      float rs = p0 + p1 + 1e-20f;
      topE[t * 2] = i0; topE[t * 2 + 1] = i1;
      topW[t * 2] = p0 / rs; topW[t * 2 + 1] = p1 / rs;
      atomicAdd(&hist[i0], 1);   // LDS atomic — bank speed
      atomicAdd(&hist[i1], 1);
    }
  }
  __syncthreads();
  if (tid < ED) atomicAdd(&counts[tid], hist[tid]);  // 8 global atomics/block
}

// ---------------- plan: segment bases, cursors, tile table ----------------
__global__ __launch_bounds__(256) void k_plan(const int* __restrict__ counts, int* cursor,
    int* __restrict__ tileE, int* __restrict__ tileEnd) {
  __shared__ int tstart[ED + 1], segend[ED];
  if (threadIdx.x == 0) {
    int base = T_TOK, rt = TILE_SHARED;
    for (int e = 0; e < ED; ++e) {
      int c = counts[e];
      cursor[e] = base;
      tstart[e] = rt;
      segend[e] = base + c;
      int tiles = (c + BM - 1) >> 7;
      rt += tiles;
      base += tiles << 7;
    }
    tstart[ED] = rt;
  }
  __syncthreads();
  for (int rt = threadIdx.x; rt < TILE_MAX; rt += 256) {
    int e = -1, end = 0;
    if (rt < TILE_SHARED) { e = ED; end = T_TOK; }
    else {
      for (int q = 0; q < ED; ++q)
        if (rt >= tstart[q] && rt < tstart[q + 1]) { e = q; end = segend[q]; }
    }
    tileE[rt] = e; tileEnd[rt] = end;
  }
}

// ---------------- scatter: block-aggregated cursor allocation ----------------
// Was 16384 returning atomics on one cache line; now LDS slots + 8 global
// atomics per block (32 blocks).
__global__ __launch_bounds__(256) void k_scatter(const int* __restrict__ topE,
    const float* __restrict__ topW, int* cursor, int* tok, float* wrow) {
  __shared__ int lcount[ED], lbase[ED];
  int tid = threadIdx.x;
  if (tid < ED) lcount[tid] = 0;
  __syncthreads();
  int t = blockIdx.x * 256 + tid;
  int e0 = topE[t * 2], e1 = topE[t * 2 + 1];
  float w0 = topW[t * 2], w1 = topW[t * 2 + 1];
  int s0 = atomicAdd(&lcount[e0], 1);   // LDS
  int s1 = atomicAdd(&lcount[e1], 1);   // LDS
  __syncthreads();
  if (tid < ED) lbase[tid] = atomicAdd(&cursor[tid], lcount[tid]);  // global, 8/block
  __syncthreads();
  int p0 = lbase[e0] + s0;
  int p1 = lbase[e1] + s1;
  tok[p0] = t; wrow[p0] = w0;
  tok[p1] = t; wrow[p1] = w1;
}

// ---------------- GEMM1: hidden = silu(Xg)*(Xu), gathered rows ----------------
__global__ __launch_bounds__(256, 2) void k_gemm1(
    const unsigned short* __restrict__ xb,
    const unsigned short* __restrict__ wgt, const unsigned short* __restrict__ wut,
    const unsigned short* __restrict__ sgt, const unsigned short* __restrict__ sut,
    const int* __restrict__ tok, const int* __restrict__ tileE,
    const int* __restrict__ tileEnd, unsigned short* __restrict__ hbuf, int tileBase) {
  int lt = blockIdx.y;
  int rt = tileBase + lt;
  int e = tileE[rt];
  if (e < 0) return;
  int n0 = blockIdx.x * BM;
  int grow0 = rt * BM;   // global assignment-row base
  int hrow0 = lt * BM;   // chunk-local hbuf row base
  int segEnd = tileEnd[rt];
  const unsigned short* bg = (e == ED) ? sgt : wgt + (size_t)e * DD * HD;
  const unsigned short* bu = (e == ED) ? sut : wut + (size_t)e * DD * HD;

  __shared__ __align__(16) unsigned short As[BM * BK];
  __shared__ __align__(16) unsigned short Bg[BM * BK];
  __shared__ __align__(16) unsigned short Bu[BM * BK];

  int tid = threadIdx.x, lane = tid & 63, wave = tid >> 6;
  int wm = (wave & 1) * 64, wn = (wave >> 1) * 64;
  int kc = lane & 3;

  int ldsU[2];
  const unsigned short *pA[2], *pBg[2], *pBu[2];
#pragma unroll
  for (int r = 0; r < 2; ++r) {
    int chunk = r * 4 + wave;
    int idx = chunk * 64 + lane;
    int row = idx >> 2;
    ldsU[r] = chunk * 512;
    pA[r]  = xb + (size_t)tok[grow0 + row] * HD + kc * 8;
    pBg[r] = bg + (size_t)(n0 + row) * HD + kc * 8;
    pBu[r] = bu + (size_t)(n0 + row) * HD + kc * 8;
  }

  f32x4 zero = {0.f, 0.f, 0.f, 0.f};
  f32x4 accg[4][4], accu[4][4];
#pragma unroll
  for (int i = 0; i < 4; ++i)
#pragma unroll
    for (int j = 0; j < 4; ++j) { accg[i][j] = zero; accu[i][j] = zero; }

  for (int k0 = 0; k0 < HD; k0 += BK) {
#pragma unroll
    for (int r = 0; r < 2; ++r) {
      gll16(pA[r] + k0,  As + ldsU[r]);
      gll16(pBg[r] + k0, Bg + ldsU[r]);
      gll16(pBu[r] + k0, Bu + ldsU[r]);
    }
    __syncthreads();
    short8 af[4], bgf[4], buf_[4];
    int qk = (lane >> 4) * 8;
#pragma unroll
    for (int i = 0; i < 4; ++i) {
      af[i]   = *(const short8*)(As + (wm + i * 16 + (lane & 15)) * BK + qk);
      bgf[i]  = *(const short8*)(Bg + (wn + i * 16 + (lane & 15)) * BK + qk);
      buf_[i] = *(const short8*)(Bu + (wn + i * 16 + (lane & 15)) * BK + qk);
    }
#pragma unroll
    for (int i = 0; i < 4; ++i)
#pragma unroll
      for (int j = 0; j < 4; ++j) {
        accg[i][j] = __builtin_amdgcn_mfma_f32_16x16x32_bf16(af[i], bgf[j],  accg[i][j], 0, 0, 0);
        accu[i][j] = __builtin_amdgcn_mfma_f32_16x16x32_bf16(af[i], buf_[j], accu[i][j], 0, 0, 0);
      }
    __syncthreads();
  }

  int colB = n0 + wn + (lane & 15);
  int rowB = wm + ((lane >> 4) << 2);
#pragma unroll
  for (int i = 0; i < 4; ++i)
#pragma unroll
    for (int j = 0; j < 4; ++j)
#pragma unroll
      for (int r = 0; r < 4; ++r) {
        int lr = rowB + i * 16 + r;
        float g = accg[i][j][r], u = accu[i][j][r];
        float h = (grow0 + lr < segEnd) ? (g / (1.0f + __expf(-g))) * u : 0.0f;
        hbuf[(size_t)(hrow0 + lr) * DD + colB + j * 16] = f2bf(h);
      }
}

// ---------------- GEMM2: out[tok] += (hidden @ Wd^T) * wrow (atomic) ----------------
__global__ __launch_bounds__(256, 2) void k_gemm2(
    const unsigned short* __restrict__ hbuf,
    const unsigned short* __restrict__ wdt, const unsigned short* __restrict__ sdt,
    const int* __restrict__ tok, const int* __restrict__ tileE,
    const int* __restrict__ tileEnd, const float* __restrict__ wrow,
    float* __restrict__ outp, int tileBase) {
  int lt = blockIdx.y;
  int rt = tileBase + lt;
  int e = tileE[rt];
  if (e < 0) return;
  int n0 = blockIdx.x * BM;
  int grow0 = rt * BM;
  int hrow0 = lt * BM;
  int segEnd = tileEnd[rt];
  const unsigned short* bd = (e == ED) ? sdt : wdt + (size_t)e * HD * DD;

  __shared__ __align__(16) unsigned short As[BM * BK];
  __shared__ __align__(16) unsigned short Bs[BM * BK];

  int tid = threadIdx.x, lane = tid & 63, wave = tid >> 6;
  int wm = (wave & 1) * 64, wn = (wave >> 1) * 64;
  int kc = lane & 3;

  int ldsU[2];
  const unsigned short *pA[2], *pB[2];
#pragma unroll
  for (int r = 0; r < 2; ++r) {
    int chunk = r * 4 + wave;
    int idx = chunk * 64 + lane;
    int row = idx >> 2;
    ldsU[r] = chunk * 512;
    pA[r] = hbuf + (size_t)(hrow0 + row) * DD + kc * 8;
    pB[r] = bd + (size_t)(n0 + row) * DD + kc * 8;
  }

  f32x4 zero = {0.f, 0.f, 0.f, 0.f};
  f32x4 acc[4][4];
#pragma unroll
  for (int i = 0; i < 4; ++i)
#pragma unroll
    for (int j = 0; j < 4; ++j) acc[i][j] = zero;

  for (int k0 = 0; k0 < DD; k0 += BK) {
#pragma unroll
    for (int r = 0; r < 2; ++r) {
      gll16(pA[r] + k0, As + ldsU[r]);
      gll16(pB[r] + k0, Bs + ldsU[r]);
    }
    __syncthreads();
    short8 af[4], bf[4];
    int qk = (lane >> 4) * 8;
#pragma unroll
    for (int i = 0; i < 4; ++i) {
      af[i] = *(const short8*)(As + (wm + i * 16 + (lane & 15)) * BK + qk);
      bf[i] = *(const short8*)(Bs + (wn + i * 16 + (lane & 15)) * BK + qk);
    }
#pragma unroll
    for (int i = 0; i < 4; ++i)
#pragma unroll
      for (int j = 0; j < 4; ++j)
        acc[i][j] = __builtin_amdgcn_mfma_f32_16x16x32_bf16(af[i], bf[j], acc[i][j], 0, 0, 0);
    __syncthreads();
  }

  int colB = n0 + wn + (lane & 15);
  int rowB = wm + ((lane >> 4) << 2);
#pragma unroll
  for (int i = 0; i < 4; ++i)
#pragma unroll
    for (int r = 0; r < 4; ++r) {
      int grr = grow0 + rowB + i * 16 + r;
      if (grr < segEnd) {
        float w = wrow[grr];
        size_t ob = (size_t)tok[grr] * HD;
#pragma unroll
        for (int j = 0; j < 4; ++j)
          atomicAdd(&outp[ob + colB + j * 16], acc[i][j][r] * w);
      }
    }
}

extern "C" void kernel_launch(void* const* d_in, const int* in_sizes, int n_in,
                              void* d_out, int out_size, void* d_ws, size_t ws_size,
                              hipStream_t stream) {
  const float* x  = (const float*)d_in[0];
  const float* Wr = (const float*)d_in[1];
  const float* Wg = (const float*)d_in[2];
  const float* Wu = (const float*)d_in[3];
  const float* Wd = (const float*)d_in[4];
  const float* Sg = (const float*)d_in[5];
  const float* Su = (const float*)d_in[6];
  const float* Sd = (const float*)d_in[7];
  float* outp = (float*)d_out;

  char* ws = (char*)d_ws;
  size_t off = 0;
  auto alloc = [&](size_t bytes) -> char* {
    char* p = ws + off;
    off += (bytes + 255) & ~(size_t)255;
    return p;
  };
  unsigned short* xb  = (unsigned short*)alloc((size_t)T_TOK * HD * 2);
  unsigned short* wgt = (unsigned short*)alloc((size_t)ED * DD * HD * 2);
  unsigned short* wut = (unsigned short*)alloc((size_t)ED * DD * HD * 2);
  unsigned short* wdt = (unsigned short*)alloc((size_t)ED * HD * DD * 2);
  unsigned short* sgt = (unsigned short*)alloc((size_t)DD * HD * 2);
  unsigned short* sut = (unsigned short*)alloc((size_t)DD * HD * 2);
  unsigned short* sdt = (unsigned short*)alloc((size_t)HD * DD * 2);
  unsigned short* hbuf = (unsigned short*)alloc((size_t)CHUNK_T * BM * DD * 2);
  int* tok       = (int*)alloc((size_t)ROWCAP * 4);
  float* wrow    = (float*)alloc((size_t)ROWCAP * 4);
  int* topE      = (int*)alloc((size_t)T_TOK * 2 * 4);
  float* topW    = (float*)alloc((size_t)T_TOK * 2 * 4);
  int* counts    = (int*)alloc(128);
  int* cursor    = (int*)alloc(128);
  int* tileE     = (int*)alloc(256 * 4);
  int* tileEnd   = (int*)alloc(256 * 4);

  if (off > ws_size) return;

  k_zero<<<(out_size / 4 + 255) / 256, 256, 0, stream>>>(outp);
  k_init<<<(ROWCAP + 255) / 256, 256, 0, stream>>>(counts, tok, wrow);
  k_transpose<<<dim3(DD / 32, HD / 32, ED), 256, 0, stream>>>(Wg, wgt, HD, DD);
  k_transpose<<<dim3(DD / 32, HD / 32, ED), 256, 0, stream>>>(Wu, wut, HD, DD);
  k_transpose<<<dim3(HD / 32, DD / 32, ED), 256, 0, stream>>>(Wd, wdt, DD, HD);
  k_transpose<<<dim3(DD / 32, HD / 32, 1), 256, 0, stream>>>(Sg, sgt, HD, DD);
  k_transpose<<<dim3(DD / 32, HD / 32, 1), 256, 0, stream>>>(Su, sut, HD, DD);
  k_transpose<<<dim3(HD / 32, DD / 32, 1), 256, 0, stream>>>(Sd, sdt, DD, HD);
  k_router<<<T_TOK / (4 * RT_TPW), 256, 0, stream>>>(x, Wr, xb, counts, topE, topW);
  k_plan<<<1, 256, 0, stream>>>(counts, cursor, tileE, tileEnd);
  k_scatter<<<T_TOK / 256, 256, 0, stream>>>(topE, topW, cursor, tok, wrow);
  for (int cb = 0; cb < TILE_MAX; cb += CHUNK_T) {
    k_gemm1<<<dim3(DD / BM, CHUNK_T), 256, 0, stream>>>(xb, wgt, wut, sgt, sut, tok,
                                                        tileE, tileEnd, hbuf, cb);
    k_gemm2<<<dim3(HD / BM, CHUNK_T), 256, 0, stream>>>(hbuf, wdt, sdt, tok, tileE,
                                                        tileEnd, wrow, outp, cb);
  }
}

// Round 5
// 762.264 us; speedup vs baseline: 1.3770x; 1.0688x over previous
//
#include <hip/hip_runtime.h>
#include <stdint.h>

#define T_TOK 8192
#define HD 1024
#define ED 8
#define DD 2048
#define BM 128
#define BK 32
#define TILE_SHARED 64   // T_TOK/BM shared-expert tiles
#define TILE_MAX 200     // 64 shared + max 136 routed tiles
#define ROWCAP 25600     // 8192 shared + 17408 padded routed rows
#define RT_TPW 8         // router: tokens per wave (32/block, 256 blocks)

typedef short short8 __attribute__((ext_vector_type(8)));
typedef float f32x4 __attribute__((ext_vector_type(4)));

__device__ __forceinline__ unsigned short f2bf(float f) {
  union { float f; unsigned int u; } v; v.f = f;
  unsigned int r = (v.u + 0x7fffu + ((v.u >> 16) & 1u)) >> 16;
  return (unsigned short)r;
}

__device__ __forceinline__ void gll16(const void* g, void* l) {
  __builtin_amdgcn_global_load_lds(
      (const __attribute__((address_space(1))) unsigned int*)g,
      (__attribute__((address_space(3))) unsigned int*)l, 16, 0, 0);
}

// ---------------- zero d_out ----------------
__global__ __launch_bounds__(256) void k_zero(float* __restrict__ outp) {
  size_t i = (size_t)blockIdx.x * 256 + threadIdx.x;
  ((float4*)outp)[i] = make_float4(0.f, 0.f, 0.f, 0.f);
}

// ---------------- init: counts + default assignment table ----------------
__global__ __launch_bounds__(256) void k_init(int* counts, int* tok, float* wrow) {
  int i = blockIdx.x * 256 + threadIdx.x;
  if (i < 32) counts[i] = 0;
  if (i < ROWCAP) {
    tok[i] = (i < T_TOK) ? i : 0;          // shared segment = identity; pads -> token 0
    wrow[i] = (i < T_TOK) ? 1.0f : 0.0f;   // shared weight 1, pads weight 0
  }
}

// ---------------- transpose+convert: in[R][C] fp32 -> out[C][R] bf16 ----------------
__global__ __launch_bounds__(256) void k_transpose(const float* __restrict__ in,
    unsigned short* __restrict__ outp, int R, int C) {
  __shared__ float tile[32][33];
  size_t boff = (size_t)blockIdx.z * (size_t)R * (size_t)C;
  in += boff; outp += boff;
  int c0 = blockIdx.x * 32, r0 = blockIdx.y * 32;
  int tx = threadIdx.x & 31, ty = threadIdx.x >> 5;
#pragma unroll
  for (int i = 0; i < 4; ++i)
    tile[ty + i * 8][tx] = in[(size_t)(r0 + ty + i * 8) * C + c0 + tx];
  __syncthreads();
#pragma unroll
  for (int i = 0; i < 4; ++i)
    outp[(size_t)(c0 + ty + i * 8) * R + r0 + tx] = f2bf(tile[tx][ty + i * 8]);
}

// ---------------- router: x->bf16, logits, softmax, top2, LDS histogram ----------------
__global__ __launch_bounds__(256) void k_router(const float* __restrict__ x,
    const float* __restrict__ Wr, unsigned short* __restrict__ xb,
    int* __restrict__ counts, int* __restrict__ topE, float* __restrict__ topW) {
  __shared__ float wrT[ED * HD];  // [e][h]
  __shared__ int hist[ED];
  int tid = threadIdx.x;
  if (tid < ED) hist[tid] = 0;
  for (int i = tid; i < ED * HD; i += 256) {
    int e = i >> 10, h = i & (HD - 1);
    wrT[i] = Wr[h * ED + e];
  }
  __syncthreads();
  int lane = tid & 63, wave = tid >> 6;
  int tbase = (blockIdx.x * 4 + wave) * RT_TPW;
  for (int tt = 0; tt < RT_TPW; ++tt) {
    int t = tbase + tt;
    const float* xrow = x + (size_t)t * HD;
    unsigned short* xbrow = xb + (size_t)t * HD;
    float acc[ED] = {0, 0, 0, 0, 0, 0, 0, 0};
#pragma unroll
    for (int i = 0; i < HD / 64; ++i) {
      int h = i * 64 + lane;
      float v = xrow[h];
      xbrow[h] = f2bf(v);
#pragma unroll
      for (int e = 0; e < ED; ++e) acc[e] += v * wrT[e * HD + h];
    }
#pragma unroll
    for (int off = 32; off; off >>= 1)
#pragma unroll
      for (int e = 0; e < ED; ++e) acc[e] += __shfl_xor(acc[e], off);
    if (lane == 0) {
      float m = acc[0];
#pragma unroll
      for (int e = 1; e < ED; ++e) m = fmaxf(m, acc[e]);
      float p[ED], s = 0.f;
#pragma unroll
      for (int e = 0; e < ED; ++e) { p[e] = __expf(acc[e] - m); s += p[e]; }
      int i0 = 0;
#pragma unroll
      for (int e = 1; e < ED; ++e) if (acc[e] > acc[i0]) i0 = e;
      int i1 = -1;
#pragma unroll
      for (int e = 0; e < ED; ++e) {
        if (e == i0) continue;
        if (i1 < 0 || acc[e] > acc[i1]) i1 = e;
      }
      float p0 = p[i0] / s, p1 = p[i1] / s;
      float rs = p0 + p1 + 1e-20f;
      topE[t * 2] = i0; topE[t * 2 + 1] = i1;
      topW[t * 2] = p0 / rs; topW[t * 2 + 1] = p1 / rs;
      atomicAdd(&hist[i0], 1);   // LDS atomic — bank speed
      atomicAdd(&hist[i1], 1);
    }
  }
  __syncthreads();
  if (tid < ED) atomicAdd(&counts[tid], hist[tid]);  // 8 global atomics/block
}

// ---------------- plan: segment bases, cursors, tile table ----------------
__global__ __launch_bounds__(256) void k_plan(const int* __restrict__ counts, int* cursor,
    int* __restrict__ tileE, int* __restrict__ tileEnd) {
  __shared__ int tstart[ED + 1], segend[ED];
  if (threadIdx.x == 0) {
    int base = T_TOK, rt = TILE_SHARED;
    for (int e = 0; e < ED; ++e) {
      int c = counts[e];
      cursor[e] = base;
      tstart[e] = rt;
      segend[e] = base + c;
      int tiles = (c + BM - 1) >> 7;
      rt += tiles;
      base += tiles << 7;
    }
    tstart[ED] = rt;
  }
  __syncthreads();
  for (int rt = threadIdx.x; rt < TILE_MAX; rt += 256) {
    int e = -1, end = 0;
    if (rt < TILE_SHARED) { e = ED; end = T_TOK; }
    else {
      for (int q = 0; q < ED; ++q)
        if (rt >= tstart[q] && rt < tstart[q + 1]) { e = q; end = segend[q]; }
    }
    tileE[rt] = e; tileEnd[rt] = end;
  }
}

// ---------------- scatter: block-aggregated cursor allocation ----------------
__global__ __launch_bounds__(256) void k_scatter(const int* __restrict__ topE,
    const float* __restrict__ topW, int* cursor, int* tok, float* wrow) {
  __shared__ int lcount[ED], lbase[ED];
  int tid = threadIdx.x;
  if (tid < ED) lcount[tid] = 0;
  __syncthreads();
  int t = blockIdx.x * 256 + tid;
  int e0 = topE[t * 2], e1 = topE[t * 2 + 1];
  float w0 = topW[t * 2], w1 = topW[t * 2 + 1];
  int s0 = atomicAdd(&lcount[e0], 1);   // LDS
  int s1 = atomicAdd(&lcount[e1], 1);   // LDS
  __syncthreads();
  if (tid < ED) lbase[tid] = atomicAdd(&cursor[tid], lcount[tid]);  // global, 8/block
  __syncthreads();
  int p0 = lbase[e0] + s0;
  int p1 = lbase[e1] + s1;
  tok[p0] = t; wrow[p0] = w0;
  tok[p1] = t; wrow[p1] = w1;
}

// LDS bank-conflict swizzle (R4): slot(row,c) = c ^ ((row>>1)&3).
// Staging lane fetches global k-chunk (lane&3)^((lane>>3)&3); fragment reads use
// lane-constant slot (lane>>4)^((lane>>1)&3). Spreads each 16-lane read group
// over all 8 bank-quads at 2 lanes/bank (2-way = free, m136).

// ---------------- GEMM1: hidden = silu(Xg)*(Xu), gathered rows ----------------
__global__ __launch_bounds__(256, 2) void k_gemm1(
    const unsigned short* __restrict__ xb,
    const unsigned short* __restrict__ wgt, const unsigned short* __restrict__ wut,
    const unsigned short* __restrict__ sgt, const unsigned short* __restrict__ sut,
    const int* __restrict__ tok, const int* __restrict__ tileE,
    const int* __restrict__ tileEnd, unsigned short* __restrict__ hbuf, int tileBase) {
  int lt = blockIdx.y;
  int rt = tileBase + lt;
  int e = tileE[rt];
  if (e < 0) return;
  int n0 = blockIdx.x * BM;
  int grow0 = rt * BM;   // global assignment-row base
  int hrow0 = lt * BM;   // chunk-local hbuf row base
  int segEnd = tileEnd[rt];
  const unsigned short* bg = (e == ED) ? sgt : wgt + (size_t)e * DD * HD;
  const unsigned short* bu = (e == ED) ? sut : wut + (size_t)e * DD * HD;

  __shared__ __align__(16) unsigned short As[BM * BK];
  __shared__ __align__(16) unsigned short Bg[BM * BK];
  __shared__ __align__(16) unsigned short Bu[BM * BK];

  int tid = threadIdx.x, lane = tid & 63, wave = tid >> 6;
  int wm = (wave & 1) * 64, wn = (wave >> 1) * 64;
  int kc = (lane & 3) ^ ((lane >> 3) & 3);   // swizzled global k-chunk for staging

  int ldsU[2];
  const unsigned short *pA[2], *pBg[2], *pBu[2];
#pragma unroll
  for (int r = 0; r < 2; ++r) {
    int chunk = r * 4 + wave;
    int row = chunk * 16 + (lane >> 2);
    ldsU[r] = chunk * 512;
    pA[r]  = xb + (size_t)tok[grow0 + row] * HD + kc * 8;
    pBg[r] = bg + (size_t)(n0 + row) * HD + kc * 8;
    pBu[r] = bu + (size_t)(n0 + row) * HD + kc * 8;
  }

  f32x4 zero = {0.f, 0.f, 0.f, 0.f};
  f32x4 accg[4][4], accu[4][4];
#pragma unroll
  for (int i = 0; i < 4; ++i)
#pragma unroll
    for (int j = 0; j < 4; ++j) { accg[i][j] = zero; accu[i][j] = zero; }

  int m15 = lane & 15;
  int sl8 = (((lane >> 4) ^ ((lane >> 1) & 3)) * 8);  // lane-constant swizzled slot

  for (int k0 = 0; k0 < HD; k0 += BK) {
#pragma unroll
    for (int r = 0; r < 2; ++r) {
      gll16(pA[r] + k0,  As + ldsU[r]);
      gll16(pBg[r] + k0, Bg + ldsU[r]);
      gll16(pBu[r] + k0, Bu + ldsU[r]);
    }
    __syncthreads();
    short8 af[4], bgf[4], buf_[4];
#pragma unroll
    for (int i = 0; i < 4; ++i) {
      af[i]   = *(const short8*)(As + (wm + i * 16 + m15) * BK + sl8);
      bgf[i]  = *(const short8*)(Bg + (wn + i * 16 + m15) * BK + sl8);
      buf_[i] = *(const short8*)(Bu + (wn + i * 16 + m15) * BK + sl8);
    }
#pragma unroll
    for (int i = 0; i < 4; ++i)
#pragma unroll
      for (int j = 0; j < 4; ++j) {
        accg[i][j] = __builtin_amdgcn_mfma_f32_16x16x32_bf16(af[i], bgf[j],  accg[i][j], 0, 0, 0);
        accu[i][j] = __builtin_amdgcn_mfma_f32_16x16x32_bf16(af[i], buf_[j], accu[i][j], 0, 0, 0);
      }
    __syncthreads();
  }

  int colB = n0 + wn + m15;
  int rowB = wm + ((lane >> 4) << 2);
#pragma unroll
  for (int i = 0; i < 4; ++i)
#pragma unroll
    for (int j = 0; j < 4; ++j)
#pragma unroll
      for (int r = 0; r < 4; ++r) {
        int lr = rowB + i * 16 + r;
        float g = accg[i][j][r], u = accu[i][j][r];
        float h = (grow0 + lr < segEnd) ? (g / (1.0f + __expf(-g))) * u : 0.0f;
        hbuf[(size_t)(hrow0 + lr) * DD + colB + j * 16] = f2bf(h);
      }
}

// ---------------- GEMM2: out[tok] += (hidden @ Wd^T) * wrow (atomic) ----------------
__global__ __launch_bounds__(256, 2) void k_gemm2(
    const unsigned short* __restrict__ hbuf,
    const unsigned short* __restrict__ wdt, const unsigned short* __restrict__ sdt,
    const int* __restrict__ tok, const int* __restrict__ tileE,
    const int* __restrict__ tileEnd, const float* __restrict__ wrow,
    float* __restrict__ outp, int tileBase) {
  int lt = blockIdx.y;
  int rt = tileBase + lt;
  int e = tileE[rt];
  if (e < 0) return;
  int n0 = blockIdx.x * BM;
  int grow0 = rt * BM;
  int hrow0 = lt * BM;
  int segEnd = tileEnd[rt];
  const unsigned short* bd = (e == ED) ? sdt : wdt + (size_t)e * HD * DD;

  __shared__ __align__(16) unsigned short As[BM * BK];
  __shared__ __align__(16) unsigned short Bs[BM * BK];

  int tid = threadIdx.x, lane = tid & 63, wave = tid >> 6;
  int wm = (wave & 1) * 64, wn = (wave >> 1) * 64;
  int kc = (lane & 3) ^ ((lane >> 3) & 3);

  int ldsU[2];
  const unsigned short *pA[2], *pB[2];
#pragma unroll
  for (int r = 0; r < 2; ++r) {
    int chunk = r * 4 + wave;
    int row = chunk * 16 + (lane >> 2);
    ldsU[r] = chunk * 512;
    pA[r] = hbuf + (size_t)(hrow0 + row) * DD + kc * 8;
    pB[r] = bd + (size_t)(n0 + row) * DD + kc * 8;
  }

  f32x4 zero = {0.f, 0.f, 0.f, 0.f};
  f32x4 acc[4][4];
#pragma unroll
  for (int i = 0; i < 4; ++i)
#pragma unroll
    for (int j = 0; j < 4; ++j) acc[i][j] = zero;

  int m15 = lane & 15;
  int sl8 = (((lane >> 4) ^ ((lane >> 1) & 3)) * 8);

  for (int k0 = 0; k0 < DD; k0 += BK) {
#pragma unroll
    for (int r = 0; r < 2; ++r) {
      gll16(pA[r] + k0, As + ldsU[r]);
      gll16(pB[r] + k0, Bs + ldsU[r]);
    }
    __syncthreads();
    short8 af[4], bf[4];
#pragma unroll
    for (int i = 0; i < 4; ++i) {
      af[i] = *(const short8*)(As + (wm + i * 16 + m15) * BK + sl8);
      bf[i] = *(const short8*)(Bs + (wn + i * 16 + m15) * BK + sl8);
    }
#pragma unroll
    for (int i = 0; i < 4; ++i)
#pragma unroll
      for (int j = 0; j < 4; ++j)
        acc[i][j] = __builtin_amdgcn_mfma_f32_16x16x32_bf16(af[i], bf[j], acc[i][j], 0, 0, 0);
    __syncthreads();
  }

  int colB = n0 + wn + m15;
  int rowB = wm + ((lane >> 4) << 2);
#pragma unroll
  for (int i = 0; i < 4; ++i)
#pragma unroll
    for (int r = 0; r < 4; ++r) {
      int grr = grow0 + rowB + i * 16 + r;
      if (grr < segEnd) {
        float w = wrow[grr];
        size_t ob = (size_t)tok[grr] * HD;
#pragma unroll
        for (int j = 0; j < 4; ++j)
          atomicAdd(&outp[ob + colB + j * 16], acc[i][j][r] * w);
      }
    }
}

extern "C" void kernel_launch(void* const* d_in, const int* in_sizes, int n_in,
                              void* d_out, int out_size, void* d_ws, size_t ws_size,
                              hipStream_t stream) {
  const float* x  = (const float*)d_in[0];
  const float* Wr = (const float*)d_in[1];
  const float* Wg = (const float*)d_in[2];
  const float* Wu = (const float*)d_in[3];
  const float* Wd = (const float*)d_in[4];
  const float* Sg = (const float*)d_in[5];
  const float* Su = (const float*)d_in[6];
  const float* Sd = (const float*)d_in[7];
  float* outp = (float*)d_out;

  // Fixed part of the workspace layout
  size_t fixed = 0;
  auto pad = [](size_t b) { return (b + 255) & ~(size_t)255; };
  fixed += pad((size_t)T_TOK * HD * 2);            // xb
  fixed += pad((size_t)ED * DD * HD * 2) * 3;      // wgt, wut, wdt
  fixed += pad((size_t)DD * HD * 2) * 3;           // sgt, sut, sdt
  fixed += pad((size_t)ROWCAP * 4) * 2;            // tok, wrow
  fixed += pad((size_t)T_TOK * 2 * 4) * 2;         // topE, topW
  fixed += pad(128) * 2 + pad(1024) * 2;           // counts, cursor, tileE, tileEnd
  // Adaptive chunking: single 200-tile pass if hbuf fits, else 2x100.
  int CH = TILE_MAX;
  if (fixed + pad((size_t)CH * BM * DD * 2) > ws_size) CH = TILE_MAX / 2;
  if (fixed + pad((size_t)CH * BM * DD * 2) > ws_size) return;  // diagnostic failure

  char* ws = (char*)d_ws;
  size_t off = 0;
  auto alloc = [&](size_t bytes) -> char* {
    char* p = ws + off;
    off += (bytes + 255) & ~(size_t)255;
    return p;
  };
  unsigned short* xb  = (unsigned short*)alloc((size_t)T_TOK * HD * 2);
  unsigned short* wgt = (unsigned short*)alloc((size_t)ED * DD * HD * 2);
  unsigned short* wut = (unsigned short*)alloc((size_t)ED * DD * HD * 2);
  unsigned short* wdt = (unsigned short*)alloc((size_t)ED * HD * DD * 2);
  unsigned short* sgt = (unsigned short*)alloc((size_t)DD * HD * 2);
  unsigned short* sut = (unsigned short*)alloc((size_t)DD * HD * 2);
  unsigned short* sdt = (unsigned short*)alloc((size_t)HD * DD * 2);
  int* tok       = (int*)alloc((size_t)ROWCAP * 4);
  float* wrow    = (float*)alloc((size_t)ROWCAP * 4);
  int* topE      = (int*)alloc((size_t)T_TOK * 2 * 4);
  float* topW    = (float*)alloc((size_t)T_TOK * 2 * 4);
  int* counts    = (int*)alloc(128);
  int* cursor    = (int*)alloc(128);
  int* tileE     = (int*)alloc(1024);
  int* tileEnd   = (int*)alloc(1024);
  unsigned short* hbuf = (unsigned short*)alloc((size_t)CH * BM * DD * 2);

  k_zero<<<(out_size / 4 + 255) / 256, 256, 0, stream>>>(outp);
  k_init<<<(ROWCAP + 255) / 256, 256, 0, stream>>>(counts, tok, wrow);
  k_transpose<<<dim3(DD / 32, HD / 32, ED), 256, 0, stream>>>(Wg, wgt, HD, DD);
  k_transpose<<<dim3(DD / 32, HD / 32, ED), 256, 0, stream>>>(Wu, wut, HD, DD);
  k_transpose<<<dim3(HD / 32, DD / 32, ED), 256, 0, stream>>>(Wd, wdt, DD, HD);
  k_transpose<<<dim3(DD / 32, HD / 32, 1), 256, 0, stream>>>(Sg, sgt, HD, DD);
  k_transpose<<<dim3(DD / 32, HD / 32, 1), 256, 0, stream>>>(Su, sut, HD, DD);
  k_transpose<<<dim3(HD / 32, DD / 32, 1), 256, 0, stream>>>(Sd, sdt, DD, HD);
  k_router<<<T_TOK / (4 * RT_TPW), 256, 0, stream>>>(x, Wr, xb, counts, topE, topW);
  k_plan<<<1, 256, 0, stream>>>(counts, cursor, tileE, tileEnd);
  k_scatter<<<T_TOK / 256, 256, 0, stream>>>(topE, topW, cursor, tok, wrow);
  for (int cb = 0; cb < TILE_MAX; cb += CH) {
    k_gemm1<<<dim3(DD / BM, CH), 256, 0, stream>>>(xb, wgt, wut, sgt, sut, tok,
                                                   tileE, tileEnd, hbuf, cb);
    k_gemm2<<<dim3(HD / BM, CH), 256, 0, stream>>>(hbuf, wdt, sdt, tok, tileE,
                                                   tileEnd, wrow, outp, cb);
  }
}